// Round 6
// baseline (116.535 us; speedup 1.0000x reference)
//
#include <hip/hip_runtime.h>

#define BATCH_N 65536
#define SEQ_N   128
#define ELB     128               // elements per block
#define NPH     9                 // phases: producers fill 0..7, consumers step 1..8

// Native clang vector type — accepted by __builtin_nontemporal_load/store.
typedef float v2f __attribute__((ext_vector_type(2)));

// Producer/consumer wave specialization. 512 blocks x 256 threads = 131072
// threads = 2048 waves = 2 waves/SIMD (vs 1 before): the HW scheduler
// overlaps one wave's stalls with the other wave's instructions at runtime.
//   waves 0-1 (tid < 128): CONSUMERS — s-chain recurrence + NT stores only.
//   waves 2-3 (tid >= 128): PRODUCERS — global loads + d-chain precompute;
//     hand (t, M) and new-d to consumers via double-buffered LDS.
// Phase p: producers pre chunk p into buf[p&1] (+ prefetch chunk p+2 into
// registers); consumers step chunk p-1 from buf[(p-1)&1]. One barrier per
// phase. The barrier is a manual lgkmcnt(0) fence + s_barrier — NOT
// __syncthreads(), which would drain vmcnt(0) and serialize the producers'
// global prefetch stream every phase (the m97-ceiling failure mode).
// M = success ? (11-d_old)*hb : -(w11*d_old^-w12); sign(M) encodes branch.
// Consumer step: 4 transcendentals (rcp, log, 2x exp2) + ~16 VALU;
// P = (exp2(aa+x) - exp2(sel?aa:x)) * m merges success/failure algebra.
__global__ __launch_bounds__(256, 2) void fsrs_kernel(
    const v2f* __restrict__ in,   // (SEQ, BATCH) of (t, rating)
    const float* __restrict__ w,  // 17 weights
    v2f*       __restrict__ out)  // (SEQ, BATCH) of (s, d) then (BATCH) final
{
    const int tid = threadIdx.x;
    const int ew  = tid & (ELB - 1);          // element within block
    const int b   = blockIdx.x * ELB + ew;
    const bool isProd = tid >= ELB;           // wave-uniform role

    __shared__ v2f   lTM[2][16][ELB];         // (t, M)  — 32 KB
    __shared__ float lD [2][16][ELB];         // new-d   — 16 KB

    const float w0 = w[0], w1 = w[1], w2 = w[2], w3 = w[3];
    const float w4 = w[4], w5 = w[5], w6 = w[6], w7 = w[7];
    const float w9 = w[9], w11 = w[11], w12 = w[12], w13 = w[13];
    const float w15 = w[15], w16 = w[16];
    constexpr float LOG2E = 1.44269504088896340736f;
    const float w8l  = w[8]  * LOG2E;   // exp(w8)*s^-w9 = exp2(w8l - w9*log2 s)
    const float w10l = w[10] * LOG2E;
    const float w14l = w[14] * LOG2E;
    const float omw7   = 1.0f - w7;
    const float omw7w6 = omw7 * w6;
    const float dc0    = w7 * w4 + 3.0f * omw7w6;

    const v2f* ip = in  + b;
    v2f*       op = out + b;

    // producer state (only live in producer waves)
    v2f raw0[16], raw1[16];                   // even / odd chunk prefetch
    float dpre = 1.0f;                        // d-chain (runs 1 chunk ahead)
    // consumer state (only live in consumer waves)
    float s = 0.01f, dcur = 1.0f;

    if (isProd) {   // preload chunks 0, 1
#pragma unroll
        for (int i = 0; i < 16; ++i) raw0[i] = ip[i * BATCH_N];
#pragma unroll
        for (int i = 0; i < 16; ++i) raw1[i] = ip[(16 + i) * BATCH_N];
    }

#pragma unroll
    for (int p = 0; p < NPH; ++p) {
        if (isProd && p < 8) {
            const int par = p & 1;
            v2f* rw = par ? raw1 : raw0;      // static after full unroll
            int i0 = 0;
            if (p == 0) {   // chunk 0 row 0: _first_step d0; rating -> M slot
                const float t0 = rw[0].x, r0 = rw[0].y;
                const float d0 = fminf(fmaxf(
                    __builtin_fmaf(-w5, r0 - 3.0f, w4), 1.0f), 10.0f);
                dpre = d0;
                v2f tm; tm.x = t0; tm.y = r0;
                lTM[0][0][ew] = tm;
                lD [0][0][ew] = d0;
                rw[0] = ip[32 * BATCH_N];     // prefetch ch2 row 0
                i0 = 1;
            }
#pragma unroll
            for (int i = 0; i < 16; ++i) {
                if (i < i0) continue;
                const float tt = rw[i].x, rating = rw[i].y;
                const float hb = (rating == 2.0f) ? w15
                               : ((rating == 4.0f) ? w16 : 1.0f);
                const float eh = (11.0f - dpre) * hb;
                const float m2 = w11 * __builtin_amdgcn_exp2f(
                                     -w12 * __builtin_amdgcn_logf(dpre));
                const float M  = (rating > 1.0f) ? eh : -m2;
                const float nd = __builtin_fmaf(omw7, dpre,
                                  __builtin_fmaf(-omw7w6, rating, dc0));
                dpre = fminf(fmaxf(nd, 1.0f), 10.0f);
                v2f tm; tm.x = tt; tm.y = M;
                lTM[par][i][ew] = tm;
                lD [par][i][ew] = dpre;
                if (p < 6) rw[i] = ip[((p + 2) * 16 + i) * BATCH_N];
            }
        }
        if (!isProd && p >= 1) {
            const int k   = p - 1;            // chunk being stepped
            const int par = k & 1;
            int i0 = 0;
            if (p == 1) {   // row 0 special: s0 from weight table (rating in M slot)
                const v2f tm0 = lTM[0][0][ew];
                const float r0 = tm0.y;
                const float wsel = (r0 < 2.5f) ? ((r0 < 1.5f) ? w0 : w1)
                                               : ((r0 < 3.5f) ? w2 : w3);
                const float ns = (r0 >= 1.0f && r0 <= 4.0f) ? wsel : 1.0f;
                s = fminf(fmaxf(ns, 0.01f), 36500.0f);
                dcur = lD[0][0][ew];
                v2f o; o.x = s; o.y = dcur;
                __builtin_nontemporal_store(o, &op[0]);
                i0 = 1;
            }
#pragma unroll
            for (int i = 0; i < 16; ++i) {
                if (i < i0) continue;
                const v2f  tm = lTM[par][i][ew];
                const float dd = lD[par][i][ew];
                const float tt = tm.x, ms = tm.y;
                const bool  sel = ms > 0.0f;                    // success?
                const float q   = __builtin_fmaf(9.0f, s, tt);  // 9s + t
                const float omr = tt * __builtin_amdgcn_rcpf(q);// 1 - r
                const float x   = omr * (sel ? w10l : w14l);
                const float ls  = __builtin_amdgcn_logf(sel ? s : (s + 1.0f));
                const float aa  = sel ? __builtin_fmaf(-w9, ls, w8l)
                                      : (w13 * ls);
                const float u   = __builtin_amdgcn_exp2f(aa + x);       // A*e
                const float v   = __builtin_amdgcn_exp2f(sel ? aa : x); // A | e
                const float m   = sel ? (ms * s) : (-ms);
                const float P   = (u - v) * m;
                const float su  = fminf(s + P, 36500.0f);
                const float fl  = fmaxf(fminf(P, s), 0.01f);
                s = sel ? su : fl;
                dcur = dd;
                v2f o; o.x = s; o.y = dcur;
                __builtin_nontemporal_store(o, &op[(k * 16 + i) * BATCH_N]);
            }
        }
        // Phase boundary: LDS-only fence + workgroup barrier. Global
        // prefetches (vmcnt) stay in flight across the barrier. The memory-
        // clobber asms on both sides pin LDS ops to their phase.
        asm volatile("s_waitcnt lgkmcnt(0)" ::: "memory");
        __builtin_amdgcn_s_barrier();
        asm volatile("" ::: "memory");
    }

    if (!isProd) {  // final_state, appended after the (SEQ, BATCH) outputs
        v2f o; o.x = s; o.y = dcur;
        op[SEQ_N * BATCH_N] = o;
    }
}

extern "C" void kernel_launch(void* const* d_in, const int* in_sizes, int n_in,
                              void* d_out, int out_size, void* d_ws, size_t ws_size,
                              hipStream_t stream) {
    const v2f*   in = (const v2f*)d_in[0];   // (128, 65536, 2) f32
    const float* w  = (const float*)d_in[1]; // (17,) f32
    v2f* out = (v2f*)d_out;                  // 128*65536 + 65536 float2
    fsrs_kernel<<<BATCH_N / ELB, 256, 0, stream>>>(in, w, out);
}

// Round 7
// 112.668 us; speedup vs baseline: 1.0343x; 1.0343x over previous
//
#include <hip/hip_runtime.h>

#define BATCH_N 65536
#define SEQ_N   128

// Native clang vector type — accepted by __builtin_nontemporal_load/store.
typedef float v2f __attribute__((ext_vector_type(2)));

// One thread per batch element; 128-step sequential recurrence in registers.
// 65536 threads = 1024 waves = exactly 1 wave per SIMD chip-wide: no TLP, so
// ALL latency hiding must come from ILP inside the one wave (R6's 2-wave
// producer/consumer split regressed: LDS+barrier overhead > TLP gain).
// Three independent streams fused at ROW granularity (R5 structure):
//   per row i of a 16-row phase:
//     - 1 global load of chunk k+2 row i      (memory stream)
//     - preRow of chunk k+1 row i             (d-chain: ~11 VALU + 1 trans)
//     - stepRow of chunk k row i              (s-chain: ~19 VALU + 4 trans + NT store)
// Trans shave vs R5: the failure multiplier w11*d^-w12 is carried in LOG
// domain (md = fma(-w12, log2 d, log2 w11), 1 trans) and folded into the
// step's exp2 exponents — preRow's exp2 is gone (6 -> 5 trans/row).
// The success/failure flag rides in sign(D) (d in [1,10] > 0 always):
//   D = success ? +d_new : -d_new;  E = success ? (11-d_old)*hb : md.
// Step math:  success P = (exp2(aa+x) - exp2(aa)) * E * s
//             failure P = exp2(aa+x+md) - exp2(x+md)        (mult = 1)
// with aa = success ? w8l - w9*log2 s : w13*log2(s+1), x = omr*(w10l|w14l).
__global__ __launch_bounds__(256, 1) void fsrs_kernel(
    const v2f* __restrict__ in,   // (SEQ, BATCH) of (t, rating)
    const float* __restrict__ w,  // 17 weights
    v2f*       __restrict__ out)  // (SEQ, BATCH) of (s, d) then (BATCH) final
{
    const int b = blockIdx.x * 256 + threadIdx.x;

    const float w0 = w[0], w1 = w[1], w2 = w[2], w3 = w[3];
    const float w4 = w[4], w5 = w[5], w6 = w[6], w7 = w[7];
    const float w9 = w[9], w12 = w[12], w13 = w[13];
    const float w15 = w[15], w16 = w[16];
    constexpr float LOG2E = 1.44269504088896340736f;
    const float w8l  = w[8]  * LOG2E;   // exp(w8)*s^-w9 = exp2(w8l - w9*log2 s)
    const float w10l = w[10] * LOG2E;
    const float w14l = w[14] * LOG2E;
    const float lw11 = __builtin_amdgcn_logf(w[11]);   // log2(w11), one-time
    const float omw7   = 1.0f - w7;
    const float omw7w6 = omw7 * w6;
    const float dc0    = w7 * w4 + 3.0f * omw7w6;

    const v2f* ip = in  + b;
    v2f*       op = out + b;

    float s = 0.01f;       // stability state (serial s-chain)
    float dpre = 1.0f;     // d running ahead (serial d-chain, 1 chunk early)

    v2f rawA[16], rawB[16];
    float tX[16], dX[16], eX[16];   // t, signed new-d, success-mult | log-mult
    float tY[16], dY[16], eY[16];

    // Prologue-only burst load of a 16-row chunk.
    auto loadC = [&](v2f* raw, int base) {
#pragma unroll
        for (int i = 0; i < 16; ++i) raw[i] = ip[(base + i) * BATCH_N];
    };

    // d-chain row: uses/updates dpre (old d on entry). Writes:
    //   E = success ? (11-d_old)*hb : log2(w11*d_old^-w12)
    //   D = success ? +d_new : -d_new      (flag in sign; |D| = output d)
    auto preRow = [&](v2f r, float* T, float* D, float* E, int i) {
        const float tt = r.x, rating = r.y;
        const float hb = (rating == 2.0f) ? w15
                       : ((rating == 4.0f) ? w16 : 1.0f);
        const float eh = (11.0f - dpre) * hb;
        const float md = __builtin_fmaf(-w12,
                             __builtin_amdgcn_logf(dpre), lw11);
        const bool ok  = rating > 1.0f;
        E[i] = ok ? eh : md;
        const float nd = __builtin_fmaf(omw7, dpre,
                          __builtin_fmaf(-omw7w6, rating, dc0));
        dpre = fminf(fmaxf(nd, 1.0f), 10.0f);
        T[i] = tt;
        D[i] = ok ? dpre : -dpre;
    };

    // s-chain row + NT store. Branch = sign(dd); md folded into exponents on
    // the failure path; failure clamp = med3(P, 0.01, s) = max(min(P,s),0.01).
    auto stepRow = [&](float tt, float ee, float dd, int row) {
        const bool  sel = dd > 0.0f;                    // success?
        const float dc  = __builtin_fabsf(dd);
        const float q   = __builtin_fmaf(9.0f, s, tt);  // 9s + t
        const float omr = tt * __builtin_amdgcn_rcpf(q);// 1 - r
        const float x   = omr * (sel ? w10l : w14l);
        const float ls  = __builtin_amdgcn_logf(sel ? s : (s + 1.0f));
        const float aa  = sel ? __builtin_fmaf(-w9, ls, w8l) : (w13 * ls);
        const float g   = sel ? 0.0f : ee;              // exponent addend (md)
        const float xg  = x + g;
        const float u   = __builtin_amdgcn_exp2f(aa + xg);
        const float v   = __builtin_amdgcn_exp2f(sel ? aa : xg);
        const float mm  = sel ? (ee * s) : 1.0f;
        const float P   = (u - v) * mm;
        const float su  = fminf(s + P, 36500.0f);
        const float fl  = __builtin_amdgcn_fmed3f(P, 0.01f, s);
        s = sel ? su : fl;
        v2f o; o.x = s; o.y = dc;
        __builtin_nontemporal_store(o, &op[row * BATCH_N]);
    };

    // Prologue-only plain precompute of a chunk (no step material yet).
    auto preC = [&](const v2f* raw, float* T, float* D, float* E, int lo) {
#pragma unroll
        for (int i = 0; i < 16; ++i) {
            if (i < lo) continue;
            preRow(raw[i], T, D, E, i);
        }
    };

    // Fused phase: per row — load chunk lb row i into rawDst, preRow chunk
    // from rawSrc into (T2,D2,E2), step chunk sb row i from (T,D,E).
    auto fused = [&](const float* T, const float* D, const float* E,
                     int sb, int lo,
                     const v2f* rawSrc, float* T2, float* D2, float* E2,
                     bool doPre, v2f* rawDst, int lb, bool doLoad) {
#pragma unroll
        for (int i = 0; i < 16; ++i) {
            if (doLoad) rawDst[i] = ip[(lb + i) * BATCH_N];
            if (doPre)  preRow(rawSrc[i], T2, D2, E2, i);
            if (i >= lo) stepRow(T[i], E[i], D[i], sb + i);
        }
    };

    // ---- prologue: burst-load ch0, ch1; pre ch0; special row 0 ----
    loadC(rawA, 0);
    loadC(rawB, 16);

    const float r0 = rawA[0].y;
    {   // row 0: _first_step (d0 comes from rating only)
        const float d0 = fminf(fmaxf(
            __builtin_fmaf(-w5, r0 - 3.0f, w4), 1.0f), 10.0f);
        dpre = d0;
        tX[0] = rawA[0].x; dX[0] = d0; eX[0] = 1.0f;   // row 0 stepped specially
    }
    preC(rawA, tX, dX, eX, 1);     // ch0 -> X; rawA free

    {   // step row 0 (special): s0 from weight table
        const float wsel = (r0 < 2.5f) ? ((r0 < 1.5f) ? w0 : w1)
                                       : ((r0 < 3.5f) ? w2 : w3);
        const float ns = (r0 >= 1.0f && r0 <= 4.0f) ? wsel : 1.0f;
        s = fminf(fmaxf(ns, 0.01f), 36500.0f);
        v2f o; o.x = s; o.y = dX[0];
        __builtin_nontemporal_store(o, &op[0]);
    }

    // fused(0): step ch0 rows 1..15 | pre ch1 (rawB->Y) | load ch2 -> rawA
    fused(tX, dX, eX, 0, 1, rawB, tY, dY, eY, true, rawA, 32, true);

    // ---- main: c covers k=2c+1 (odd) and k=2c+2 (even) ----
    // fused(odd k):  step Y (ch k) | pre rawA (ch k+1) -> X | load ch k+2 -> rawB
    // fused(even k): step X (ch k) | pre rawB (ch k+1) -> Y | load ch k+2 -> rawA
#pragma unroll 1
    for (int c = 0; c < 3; ++c) {
        fused(tY, dY, eY, 16 * (2 * c + 1), 0,
              rawA, tX, dX, eX, true, rawB, 16 * (2 * c + 3), true);
        fused(tX, dX, eX, 16 * (2 * c + 2), 0,
              rawB, tY, dY, eY, true, rawA, 16 * (2 * c + 4), c < 2);
    }

    // ---- tail: fused(7): step ch7 (Y) only — no pre, no load ----
    fused(tY, dY, eY, 112, 0, rawA, tX, dX, eX, false, rawB, 0, false);

    // final_state, appended after the (SEQ, BATCH) outputs.
    {
        v2f o; o.x = s; o.y = __builtin_fabsf(dY[15]);
        op[SEQ_N * BATCH_N] = o;
    }
}

extern "C" void kernel_launch(void* const* d_in, const int* in_sizes, int n_in,
                              void* d_out, int out_size, void* d_ws, size_t ws_size,
                              hipStream_t stream) {
    const v2f*   in = (const v2f*)d_in[0];   // (128, 65536, 2) f32
    const float* w  = (const float*)d_in[1]; // (17,) f32
    v2f* out = (v2f*)d_out;                  // 128*65536 + 65536 float2
    fsrs_kernel<<<BATCH_N / 256, 256, 0, stream>>>(in, w, out);
}